// Round 2
// baseline (147.838 us; speedup 1.0000x reference)
//
#include <hip/hip_runtime.h>

#define NB 4
#define CD 256
#define HW 4096
#define KSG 16
#define CC (CD * CD)

typedef __attribute__((ext_vector_type(8))) short bf16x8;
typedef __attribute__((ext_vector_type(4))) float f32x4;
typedef __attribute__((ext_vector_type(8))) unsigned short u16x8;

__device__ inline unsigned short f2bf(float x) {
  unsigned int u = __float_as_uint(x);
  unsigned int r = (u + 0x7FFFu + ((u >> 16) & 1u)) >> 16;
  return (unsigned short)r;
}
__device__ inline float bfhi(unsigned short h) {
  return __uint_as_float(((unsigned int)h) << 16);
}

// ---------- convert X fp32 -> bf16 hi/lo, both [c][p] and transposed [p][c] ----------
__global__ __launch_bounds__(256) void k_convert(const float* __restrict__ X,
                                                 unsigned short* __restrict__ Uhi,
                                                 unsigned short* __restrict__ Ulo,
                                                 unsigned short* __restrict__ Xthi,
                                                 unsigned short* __restrict__ Xtlo) {
  int pt = blockIdx.x, ct = blockIdx.y, n = blockIdx.z;
  __shared__ unsigned int W[64][65];
  int t = threadIdx.x;
  int cl = t >> 2, pb = (t & 3) * 16;
  const float* Xp = X + ((size_t)n * CD + ct * 64 + cl) * HW + pt * 64 + pb;
  float x[16];
#pragma unroll
  for (int j = 0; j < 4; ++j) {
    float4 v = *(const float4*)(Xp + 4 * j);
    x[4 * j + 0] = v.x; x[4 * j + 1] = v.y; x[4 * j + 2] = v.z; x[4 * j + 3] = v.w;
  }
  unsigned short h[16], l[16];
#pragma unroll
  for (int j = 0; j < 16; ++j) {
    h[j] = f2bf(x[j]);
    l[j] = f2bf(x[j] - bfhi(h[j]));
    W[cl][pb + j] = (((unsigned int)h[j]) << 16) | l[j];
  }
  size_t rowOff = ((size_t)n * CD + ct * 64 + cl) * HW + pt * 64 + pb;
#pragma unroll
  for (int j = 0; j < 4; ++j) {
    ushort4 vh, vl;
    vh.x = h[4 * j]; vh.y = h[4 * j + 1]; vh.z = h[4 * j + 2]; vh.w = h[4 * j + 3];
    vl.x = l[4 * j]; vl.y = l[4 * j + 1]; vl.z = l[4 * j + 2]; vl.w = l[4 * j + 3];
    *(ushort4*)(Uhi + rowOff + 4 * j) = vh;
    *(ushort4*)(Ulo + rowOff + 4 * j) = vl;
  }
  __syncthreads();
  int pl = t >> 2, cb = (t & 3) * 16;
  size_t rowT = ((size_t)n * HW + pt * 64 + pl) * CD + ct * 64 + cb;
#pragma unroll
  for (int j = 0; j < 4; ++j) {
    ushort4 vh, vl;
    unsigned int w0v = W[cb + 4 * j + 0][pl];
    unsigned int w1v = W[cb + 4 * j + 1][pl];
    unsigned int w2v = W[cb + 4 * j + 2][pl];
    unsigned int w3v = W[cb + 4 * j + 3][pl];
    vh.x = (unsigned short)(w0v >> 16); vl.x = (unsigned short)(w0v & 0xffff);
    vh.y = (unsigned short)(w1v >> 16); vl.y = (unsigned short)(w1v & 0xffff);
    vh.z = (unsigned short)(w2v >> 16); vl.z = (unsigned short)(w2v & 0xffff);
    vh.w = (unsigned short)(w3v >> 16); vl.w = (unsigned short)(w3v & 0xffff);
    *(ushort4*)(Xthi + rowT + 4 * j) = vh;
    *(ushort4*)(Xtlo + rowT + 4 * j) = vl;
  }
}

// ---------- per-channel sums ----------
__global__ void k_chansum(const float* __restrict__ X, float* __restrict__ s) {
  int row = blockIdx.x;
  const float4* xp = (const float4*)(X + (size_t)row * HW);
  float acc = 0.f;
  for (int i = threadIdx.x; i < HW / 4; i += 256) {
    float4 v = xp[i];
    acc += v.x + v.y + v.z + v.w;
  }
  __shared__ float red[256];
  red[threadIdx.x] = acc;
  __syncthreads();
  for (int off = 128; off > 0; off >>= 1) {
    if (threadIdx.x < (unsigned)off) red[threadIdx.x] += red[threadIdx.x + off];
    __syncthreads();
  }
  if (threadIdx.x == 0) s[row] = red[0];
}

// ---------- t[n] = W1 s[n], r[n] = W0 s[n] ----------
__global__ void k_matvec(const float* __restrict__ W1, const float* __restrict__ W0,
                         const float* __restrict__ s, float* __restrict__ tvec,
                         float* __restrict__ rvec) {
  int n = blockIdx.x;
  const float* W = (blockIdx.y == 0) ? W1 : W0;
  float* outv = (blockIdx.y == 0) ? tvec : rvec;
  __shared__ float sh[CD];
  sh[threadIdx.x] = s[n * CD + threadIdx.x];
  __syncthreads();
  int i = threadIdx.x;
  float acc = 0.f;
  for (int k = 0; k < CD; ++k) acc += W[i * CD + k] * sh[k];
  outv[n * CD + i] = acc;
}

// ---------- misc vectors: alpha[n]=W2^T t, gamma[n]=W3 r, beta=W2^T b1, delta=W3 b0, v1=W1^T b2 ----------
__global__ void k_mv_misc(const float* __restrict__ w0, const float* __restrict__ w1,
                          const float* __restrict__ w2, const float* __restrict__ w3,
                          const float* __restrict__ b0, const float* __restrict__ b1,
                          const float* __restrict__ b2, const float* __restrict__ t,
                          const float* __restrict__ r, float* __restrict__ alp,
                          float* __restrict__ gam, float* __restrict__ bet,
                          float* __restrict__ dlt, float* __restrict__ v1) {
  int b = blockIdx.x, i = threadIdx.x;
  __shared__ float vin[CD];
  const float* W;
  const float* src;
  float* dst;
  int colmode;
  if (b < NB) { src = t + b * CD; W = w2; dst = alp + b * CD; colmode = 1; }
  else if (b < 2 * NB) { src = r + (b - NB) * CD; W = w3; dst = gam + (b - NB) * CD; colmode = 0; }
  else if (b == 2 * NB) { src = b1; W = w2; dst = bet; colmode = 1; }
  else if (b == 2 * NB + 1) { src = b0; W = w3; dst = dlt; colmode = 0; }
  else { src = b2; W = w1; dst = v1; colmode = 1; }
  vin[i] = src[i];
  __syncthreads();
  float acc = 0.f;
  if (colmode) {
    for (int k = 0; k < CD; ++k) acc += W[(size_t)k * CD + i] * vin[k];
  } else {
    for (int k = 0; k < CD; ++k) acc += W[(size_t)i * CD + k] * vin[k];
  }
  dst[i] = acc;
}

// ---------- cv[n] = W3 (W0 (G v1) + (t.b2) b0 + (b1.b2)(r + HW b0))/HW + b3 ----------
__global__ void k_mv2(const float* __restrict__ G, const float* __restrict__ w0,
                      const float* __restrict__ w3, const float* __restrict__ b0,
                      const float* __restrict__ b1, const float* __restrict__ b2,
                      const float* __restrict__ b3, const float* __restrict__ t,
                      const float* __restrict__ r, const float* __restrict__ v1,
                      float* __restrict__ cv) {
  int n = blockIdx.x, i = threadIdx.x;
  __shared__ float red[CD], vsh[CD], g1[CD], u[CD];
  __shared__ float scal[2];
  red[i] = t[n * CD + i] * b2[i];
  __syncthreads();
  for (int off = 128; off > 0; off >>= 1) {
    if (i < off) red[i] += red[i + off];
    __syncthreads();
  }
  if (i == 0) scal[0] = red[0];
  __syncthreads();
  red[i] = b1[i] * b2[i];
  __syncthreads();
  for (int off = 128; off > 0; off >>= 1) {
    if (i < off) red[i] += red[i + off];
    __syncthreads();
  }
  if (i == 0) scal[1] = red[0];
  vsh[i] = v1[i];
  __syncthreads();
  const float* Gn = G + (size_t)n * CC;
  float a = 0.f;
  for (int k = 0; k < CD; ++k) a += Gn[(size_t)i * CD + k] * vsh[k];
  g1[i] = a;
  __syncthreads();
  float bacc = 0.f;
  for (int k = 0; k < CD; ++k) bacc += w0[(size_t)i * CD + k] * g1[k];
  u[i] = bacc + scal[0] * b0[i] + scal[1] * (r[n * CD + i] + (float)HW * b0[i]);
  __syncthreads();
  float cacc = 0.f;
  for (int k = 0; k < CD; ++k) cacc += w3[(size_t)i * CD + k] * u[k];
  cv[n * CD + i] = cacc * (1.0f / HW) + b3[i];
}

// ---------- fp32 64x64-tile GEMM, full K=256 in 2 stages; TA: A read col-major ----------
// EPI=1: writes bf16 hi/lo At = (acc + dlt_i*alp_j + gam_i*bet_j)/HW + dlt_i*bet_j
template <int TA, int EPI>
__global__ __launch_bounds__(256) void k_gemm64(
    const float* __restrict__ A, const float* __restrict__ B, size_t aStride,
    size_t bStride, float* __restrict__ C0, size_t cStride,
    unsigned short* __restrict__ Ohi, unsigned short* __restrict__ Olo,
    const float* __restrict__ dlt, const float* __restrict__ alp,
    const float* __restrict__ gam, const float* __restrict__ bet) {
  int i0 = blockIdx.x * 64, j0 = blockIdx.y * 64, n = blockIdx.z;
  const float* An = A + (size_t)n * aStride;
  const float* Bn = B + (size_t)n * bStride;
  __shared__ __align__(16) float As[TA ? 128 * 68 : 64 * 132];
  __shared__ __align__(16) float Bs[128 * 68];
  int t = threadIdx.x, tx = t & 15, ty = t >> 4;
  float acc[4][4] = {};
  for (int s = 0; s < 2; ++s) {
    int kb = s * 128;
    if (TA == 0) {
#pragma unroll
      for (int j = 0; j < 8; ++j) {
        int flat = t + j * 256;
        int i = flat >> 5, c4 = (flat & 31) * 4;
        *(float4*)&As[i * 132 + c4] = *(const float4*)(An + (size_t)(i0 + i) * CD + kb + c4);
      }
    } else {
#pragma unroll
      for (int j = 0; j < 8; ++j) {
        int flat = t + j * 256;
        int k = flat >> 4, c4 = (flat & 15) * 4;
        *(float4*)&As[k * 68 + c4] = *(const float4*)(An + (size_t)(kb + k) * CD + i0 + c4);
      }
    }
#pragma unroll
    for (int j = 0; j < 8; ++j) {
      int flat = t + j * 256;
      int k = flat >> 4, c4 = (flat & 15) * 4;
      *(float4*)&Bs[k * 68 + c4] = *(const float4*)(Bn + (size_t)(kb + k) * CD + j0 + c4);
    }
    __syncthreads();
    for (int k = 0; k < 128; ++k) {
      float a0, a1, a2, a3;
      if (TA == 0) {
        a0 = As[(ty * 4 + 0) * 132 + k];
        a1 = As[(ty * 4 + 1) * 132 + k];
        a2 = As[(ty * 4 + 2) * 132 + k];
        a3 = As[(ty * 4 + 3) * 132 + k];
      } else {
        float4 av = *(const float4*)&As[k * 68 + ty * 4];
        a0 = av.x; a1 = av.y; a2 = av.z; a3 = av.w;
      }
      float4 bv = *(const float4*)&Bs[k * 68 + tx * 4];
      float b[4] = {bv.x, bv.y, bv.z, bv.w};
      float a[4] = {a0, a1, a2, a3};
#pragma unroll
      for (int m = 0; m < 4; ++m)
#pragma unroll
        for (int q = 0; q < 4; ++q) acc[m][q] = fmaf(a[m], b[q], acc[m][q]);
    }
    __syncthreads();
  }
  if (EPI == 0) {
    float* Cn = C0 + (size_t)n * cStride;
#pragma unroll
    for (int m = 0; m < 4; ++m)
#pragma unroll
      for (int q = 0; q < 4; ++q)
        Cn[(size_t)(i0 + ty * 4 + m) * CD + j0 + tx * 4 + q] = acc[m][q];
  } else {
#pragma unroll
    for (int m = 0; m < 4; ++m) {
      int i = i0 + ty * 4 + m;
      float di = dlt[i];
      float gi = gam[n * CD + i];
#pragma unroll
      for (int q = 0; q < 4; ++q) {
        int j = j0 + tx * 4 + q;
        float bj = bet[j];
        float aj = alp[n * CD + j];
        float v = (acc[m][q] + di * aj + gi * bj) * (1.0f / HW) + di * bj;
        unsigned short hh = f2bf(v);
        unsigned short ll = f2bf(v - bfhi(hh));
        Ohi[(size_t)n * CC + (size_t)i * CD + j] = hh;
        Olo[(size_t)n * CC + (size_t)i * CD + j] = ll;
      }
    }
  }
}

// ---------- NT MFMA GEMM (bf16 hi/lo split): C[i][j] = sum_k P[i][k] Q[j][k] ----------
// EPI=1: adds cv[n][i]. Output slot: Cout + (ks*NB + n)*cStride.
template <int EPI>
__global__ __launch_bounds__(256) void k_mfma_nt(
    const unsigned short* __restrict__ Phi, const unsigned short* __restrict__ Plo,
    size_t pStride, int ldP, const unsigned short* __restrict__ Qhi,
    const unsigned short* __restrict__ Qlo, size_t qStride, int ldQ,
    float* __restrict__ Cout, size_t cStride, int ldC, int KS, int kLen,
    const float* __restrict__ cv) {
  int z = blockIdx.z, n = z / KS, ks = z % KS;
  int i0 = blockIdx.x * 128, j0 = blockIdx.y * 128;
  int kBegin = ks * kLen;
  const unsigned short* pH = Phi + (size_t)n * pStride;
  const unsigned short* pL = Plo + (size_t)n * pStride;
  const unsigned short* qH = Qhi + (size_t)n * qStride;
  const unsigned short* qL = Qlo + (size_t)n * qStride;
  float* cPtr = Cout + ((size_t)ks * NB + n) * cStride;

  __shared__ __align__(16) unsigned short Ah[128][64];
  __shared__ __align__(16) unsigned short Al[128][64];
  __shared__ __align__(16) unsigned short Bh[128][64];
  __shared__ __align__(16) unsigned short Bl[128][64];

  int t = threadIdx.x;
  int srow = t >> 3, schk = t & 7;
  int lane = t & 63, wid = t >> 6;
  int wr = wid >> 1, wc = wid & 1;
  int lrow = lane & 15, lkb = lane >> 4;

  f32x4 acc[4][4];
#pragma unroll
  for (int m = 0; m < 4; ++m)
#pragma unroll
    for (int q = 0; q < 4; ++q) acc[m][q] = (f32x4){0.f, 0.f, 0.f, 0.f};

  for (int k0 = 0; k0 < kLen; k0 += 64) {
    int kb = kBegin + k0;
#pragma unroll
    for (int rr = 0; rr < 4; ++rr) {
      int r = rr * 32 + srow;
      int sch = (schk ^ (r & 7)) * 8;
      size_t gp = (size_t)(i0 + r) * ldP + kb + schk * 8;
      size_t gq = (size_t)(j0 + r) * ldQ + kb + schk * 8;
      *(u16x8*)&Ah[r][sch] = *(const u16x8*)(pH + gp);
      *(u16x8*)&Al[r][sch] = *(const u16x8*)(pL + gp);
      *(u16x8*)&Bh[r][sch] = *(const u16x8*)(qH + gq);
      *(u16x8*)&Bl[r][sch] = *(const u16x8*)(qL + gq);
    }
    __syncthreads();
#pragma unroll
    for (int half = 0; half < 2; ++half) {
      bf16x8 ah[4], al[4], bh[4], bl[4];
#pragma unroll
      for (int m = 0; m < 4; ++m) {
        int r = wr * 64 + m * 16 + lrow;
        int ch = ((half * 4 + lkb) ^ (r & 7)) * 8;
        ah[m] = *(const bf16x8*)&Ah[r][ch];
        al[m] = *(const bf16x8*)&Al[r][ch];
      }
#pragma unroll
      for (int q = 0; q < 4; ++q) {
        int r = wc * 64 + q * 16 + lrow;
        int ch = ((half * 4 + lkb) ^ (r & 7)) * 8;
        bh[q] = *(const bf16x8*)&Bh[r][ch];
        bl[q] = *(const bf16x8*)&Bl[r][ch];
      }
#pragma unroll
      for (int m = 0; m < 4; ++m)
#pragma unroll
        for (int q = 0; q < 4; ++q) {
          acc[m][q] = __builtin_amdgcn_mfma_f32_16x16x32_bf16(ah[m], bh[q], acc[m][q], 0, 0, 0);
          acc[m][q] = __builtin_amdgcn_mfma_f32_16x16x32_bf16(ah[m], bl[q], acc[m][q], 0, 0, 0);
          acc[m][q] = __builtin_amdgcn_mfma_f32_16x16x32_bf16(al[m], bh[q], acc[m][q], 0, 0, 0);
        }
    }
    __syncthreads();
  }
#pragma unroll
  for (int m = 0; m < 4; ++m) {
    int row = i0 + wr * 64 + m * 16 + (lane >> 4) * 4;
#pragma unroll
    for (int q = 0; q < 4; ++q) {
      int col = j0 + wc * 64 + q * 16 + (lane & 15);
#pragma unroll
      for (int e = 0; e < 4; ++e) {
        float v = acc[m][q][e];
        if (EPI == 1) v += cv[n * CD + row + e];
        cPtr[(size_t)(row + e) * ldC + col] = v;
      }
    }
  }
}

// ---------- reduce gram K-split partials ----------
__global__ void k_gram_reduce(const float* __restrict__ Gp, float* __restrict__ G) {
  size_t idx = (size_t)blockIdx.x * 256 + threadIdx.x;
  float a = 0.f;
#pragma unroll
  for (int ks = 0; ks < KSG; ++ks) a += Gp[(size_t)ks * NB * CC + idx];
  G[idx] = a;
}

extern "C" void kernel_launch(void* const* d_in, const int* in_sizes, int n_in,
                              void* d_out, int out_size, void* d_ws, size_t ws_size,
                              hipStream_t stream) {
  const float* X = (const float*)d_in[0];
  const float* w0 = (const float*)d_in[1];
  const float* b0 = (const float*)d_in[2];
  const float* w1 = (const float*)d_in[3];
  const float* b1 = (const float*)d_in[4];
  const float* w2 = (const float*)d_in[5];
  const float* b2 = (const float*)d_in[6];
  const float* w3 = (const float*)d_in[7];
  const float* b3 = (const float*)d_in[8];
  float* out = (float*)d_out;
  float* ws = (float*)d_ws;

  float* sx = ws;
  float* tv = ws + 1024;
  float* rv = ws + 2048;
  float* cv = ws + 3072;
  float* alp = ws + 4096;
  float* gam = ws + 5120;
  float* bet = ws + 6144;
  float* dlt = ws + 7168;
  float* v1 = ws + 8192;
  float* E = ws + 16384;
  float* F = E + CC;
  float* G = F + CC;            // NB*CC
  float* R = G + (size_t)NB * CC;
  unsigned short* Athi = (unsigned short*)(R + (size_t)NB * CC);
  unsigned short* Atlo = Athi + (size_t)NB * CC;
  unsigned short* Uhi = Atlo + (size_t)NB * CC;   // NB*CD*HW each
  unsigned short* Ulo = Uhi + (size_t)NB * CD * HW;
  unsigned short* Xthi = Ulo + (size_t)NB * CD * HW;
  unsigned short* Xtlo = Xthi + (size_t)NB * CD * HW;
  float* Gp = (float*)(Xtlo + (size_t)NB * CD * HW);  // KSG*NB*CC floats

  k_convert<<<dim3(HW / 64, CD / 64, NB), 256, 0, stream>>>(X, Uhi, Ulo, Xthi, Xtlo);
  k_chansum<<<dim3(NB * CD), 256, 0, stream>>>(X, sx);
  k_matvec<<<dim3(NB, 2), 256, 0, stream>>>(w1, w0, sx, tv, rv);
  k_mv_misc<<<dim3(2 * NB + 3), 256, 0, stream>>>(w0, w1, w2, w3, b0, b1, b2, tv, rv,
                                                  alp, gam, bet, dlt, v1);
  // E = W3*W0 (NN), F = W1^T*W2 (TN)
  k_gemm64<0, 0><<<dim3(4, 4, 1), 256, 0, stream>>>(w3, w0, 0, 0, E, 0, nullptr, nullptr,
                                                    nullptr, nullptr, nullptr, nullptr);
  k_gemm64<1, 0><<<dim3(4, 4, 1), 256, 0, stream>>>(w1, w2, 0, 0, F, 0, nullptr, nullptr,
                                                    nullptr, nullptr, nullptr, nullptr);
  // Gram partials via MFMA, then reduce
  k_mfma_nt<0><<<dim3(2, 2, NB * KSG), 256, 0, stream>>>(
      Uhi, Ulo, (size_t)CD * HW, HW, Uhi, Ulo, (size_t)CD * HW, HW, Gp, CC, CD, KSG,
      HW / KSG, nullptr);
  k_gram_reduce<<<dim3(NB * CC / 256), 256, 0, stream>>>(Gp, G);
  // R = E*G[n]
  k_gemm64<0, 0><<<dim3(4, 4, NB), 256, 0, stream>>>(E, G, 0, CC, R, CC, nullptr, nullptr,
                                                     nullptr, nullptr, nullptr, nullptr);
  // At = (R*F + dlt*alp^T + gam*bet^T)/HW + dlt*bet^T  -> bf16 hi/lo
  k_gemm64<0, 1><<<dim3(4, 4, NB), 256, 0, stream>>>(R, F, CC, 0, nullptr, 0, Athi, Atlo,
                                                     dlt, alp, gam, bet);
  k_mv2<<<dim3(NB), 256, 0, stream>>>(G, w0, w3, b0, b1, b2, b3, tv, rv, v1, cv);
  // out = At * Xt^T + cv
  k_mfma_nt<1><<<dim3(2, 32, NB), 256, 0, stream>>>(
      Athi, Atlo, CC, CD, Xthi, Xtlo, (size_t)HW * CD, CD, out, (size_t)CD * HW, HW, 1,
      CD, cv);
}